// Round 1
// baseline (317.333 us; speedup 1.0000x reference)
//
#include <hip/hip_runtime.h>
#include <math.h>

// Physiological constants (match reference; note E/I membrane constants are equal)
#define TAU_SYN_E 0.005f
#define TAU_SYN_I 0.01f
#define TAU_MEM   0.02f
#define U_REST    (-65.0f)
#define THETA     (-50.0f)
#define U_RESET   (-65.0f)
#define R_CONST   0.1f

#define NO_SPIKE 0x7FFFFFFF

__global__ void lif_init_tfirst(int* tf, int nb) {
    int i = threadIdx.x + blockIdx.x * blockDim.x;
    if (i < nb) tf[i] = NO_SPIKE;
}

// Independent-neuron simulation: one thread per (b, n). Assumes no recurrent
// input (valid until the first spike anywhere in the batch); records the first
// spike time per batch so the fixup kernel can repair if needed.
__global__ __launch_bounds__(64) void lif_indep(
    const int* __restrict__ n_steps_p,
    const float* __restrict__ delta_t_p,
    const float* __restrict__ init_v,
    const float* __restrict__ init_Ie,
    const float* __restrict__ init_Ii,
    float* __restrict__ out,
    int* __restrict__ tf,
    int B, int N)
{
    const int T = n_steps_p[0];
    const float dt = delta_t_p[0] * 0.001f;
    const float aE    = expf(-dt / TAU_SYN_E);
    const float aI    = expf(-dt / TAU_SYN_I);
    const float beta  = expf(-dt / TAU_MEM);
    const float drive = R_CONST * (1.0f - beta);

    int gid = blockIdx.x * blockDim.x + threadIdx.x;
    if (gid >= B * N) return;
    int b = gid / N;
    int n = gid - b * N;

    float v  = init_v[gid];
    float Ie = init_Ie[gid];
    float Ii = init_Ii[gid];

    size_t span = (size_t)B * (size_t)T * (size_t)N;
    float* __restrict__ out_s = out;
    float* __restrict__ out_v = out + span;
    float* __restrict__ out_e = out + 2 * span;
    float* __restrict__ out_i = out + 3 * span;

    size_t idx = (size_t)b * (size_t)T * (size_t)N + (size_t)n;
    bool spiked = false;

    for (int t = 0; t < T; ++t) {
        float Itot = Ie + Ii;
        v = U_REST + (v - U_REST) * beta + Itot * drive;
        float s = (v >= THETA) ? 1.0f : 0.0f;
        if (v >= THETA) {
            v = U_RESET;
            if (!spiked) { spiked = true; atomicMin(&tf[b], t); }
        }
        Ie *= aE;
        Ii *= aI;
        out_s[idx] = s;
        out_v[idx] = v;
        out_e[idx] = Ie;
        out_i[idx] = Ii;
        idx += (size_t)N;
    }
}

// Correctness fixup: if any spike occurred in batch b, re-simulate the whole
// batch with full recurrent coupling (one block per batch, spike list in LDS)
// and overwrite the outputs. No-op (immediate return) when no spikes.
__global__ __launch_bounds__(1024) void lif_fixup(
    const int* __restrict__ n_steps_p,
    const float* __restrict__ delta_t_p,
    const int* __restrict__ types,
    const float* __restrict__ W,        // raw weights (N x N), row = presynaptic
    const float* __restrict__ Ew_p,
    const float* __restrict__ Iw_p,
    const float* __restrict__ init_v,
    const float* __restrict__ init_Ie,
    const float* __restrict__ init_Ii,
    float* __restrict__ out,
    const int* __restrict__ tf,
    int B, int N)
{
    const int b = blockIdx.x;
    if (tf[b] == NO_SPIKE) return;   // batch never spiked: lif_indep output exact

    const int T = n_steps_p[0];
    const float dt = delta_t_p[0] * 0.001f;
    const float aE    = expf(-dt / TAU_SYN_E);
    const float aI    = expf(-dt / TAU_SYN_I);
    const float beta  = expf(-dt / TAU_MEM);
    const float drive = R_CONST * (1.0f - beta);
    const float Ew = Ew_p[0];
    const float Iw = Iw_p[0];

    const int NPT = (N + blockDim.x - 1) / blockDim.x;   // 4 for N=4096

    __shared__ int cnt;
    __shared__ int slist[4096];

    float v[8], Ie[8], Ii[8], sc[8];
    int   nn[8];
    for (int k = 0; k < NPT; ++k) {
        int n = threadIdx.x + k * blockDim.x;
        nn[k] = n;
        if (n < N) {
            v[k]  = init_v[(size_t)b * N + n];
            Ie[k] = init_Ie[(size_t)b * N + n];
            Ii[k] = init_Ii[(size_t)b * N + n];
            sc[k] = (types[n] == 1) ? Ew : Iw;   // column (postsynaptic) scale
        }
    }

    size_t span = (size_t)B * (size_t)T * (size_t)N;
    float* __restrict__ out_s = out;
    float* __restrict__ out_v = out + span;
    float* __restrict__ out_e = out + 2 * span;
    float* __restrict__ out_i = out + 3 * span;

    for (int t = 0; t < T; ++t) {
        if (threadIdx.x == 0) cnt = 0;
        __syncthreads();

        for (int k = 0; k < NPT; ++k) {
            if (nn[k] >= N) continue;
            float Itot = Ie[k] + Ii[k];
            float vv = U_REST + (v[k] - U_REST) * beta + Itot * drive;
            float s = (vv >= THETA) ? 1.0f : 0.0f;
            if (vv >= THETA) {
                vv = U_RESET;
                int p = atomicAdd(&cnt, 1);
                slist[p] = nn[k];
            }
            v[k] = vv;
            size_t idx = (size_t)b * (size_t)T * N + (size_t)t * N + nn[k];
            out_s[idx] = s;
            out_v[idx] = vv;
        }
        __syncthreads();

        int c = cnt;
        for (int k = 0; k < NPT; ++k) {
            if (nn[k] >= N) continue;
            float accE = 0.0f, accI = 0.0f;
            for (int q = 0; q < c; ++q) {
                int j = slist[q];
                float w = W[(size_t)j * N + nn[k]];
                if (types[j] == 1) accE += w; else accI += w;
            }
            Ie[k] = Ie[k] * aE + accE * sc[k];
            Ii[k] = Ii[k] * aI + accI * sc[k];
            size_t idx = (size_t)b * (size_t)T * N + (size_t)t * N + nn[k];
            out_e[idx] = Ie[k];
            out_i[idx] = Ii[k];
        }
        __syncthreads();
    }
}

extern "C" void kernel_launch(void* const* d_in, const int* in_sizes, int n_in,
                              void* d_out, int out_size, void* d_ws, size_t ws_size,
                              hipStream_t stream) {
    const int*   n_steps = (const int*)d_in[0];
    const float* delta_t = (const float*)d_in[1];
    const int*   types   = (const int*)d_in[2];
    const float* W       = (const float*)d_in[3];
    const float* Ew      = (const float*)d_in[4];
    const float* Iw      = (const float*)d_in[5];
    const float* init_v  = (const float*)d_in[6];
    const float* init_Ie = (const float*)d_in[7];
    const float* init_Ii = (const float*)d_in[8];
    float* out = (float*)d_out;

    const int N = in_sizes[2];
    const int B = in_sizes[6] / N;
    int* tf = (int*)d_ws;

    hipLaunchKernelGGL(lif_init_tfirst, dim3(1), dim3(64), 0, stream, tf, B);

    const int total = B * N;
    hipLaunchKernelGGL(lif_indep, dim3((total + 63) / 64), dim3(64), 0, stream,
                       n_steps, delta_t, init_v, init_Ie, init_Ii, out, tf, B, N);

    hipLaunchKernelGGL(lif_fixup, dim3(B), dim3(1024), 0, stream,
                       n_steps, delta_t, types, W, Ew, Iw,
                       init_v, init_Ie, init_Ii, out, tf, B, N);
}

// Round 2
// 316.663 us; speedup vs baseline: 1.0021x; 1.0021x over previous
//
#include <hip/hip_runtime.h>
#include <math.h>

// Physiological constants (match reference; E/I membrane constants are equal)
#define TAU_SYN_E 0.005f
#define TAU_SYN_I 0.01f
#define TAU_MEM   0.02f
#define U_REST    (-65.0f)
#define THETA     (-50.0f)
#define U_RESET   (-65.0f)
#define R_CONST   0.1f

#define NO_SPIKE 0x7FFFFFFF
#define TCHUNK 10

__global__ void lif_init_tfirst(int* tf, int nb) {
    int i = threadIdx.x + blockIdx.x * blockDim.x;
    if (i < nb) tf[i] = NO_SPIKE;
}

// Time-parallel independent-neuron simulation. Valid while no spike has
// occurred in the batch (linear dynamics -> closed-form chunk seed). Each
// block: (batch b, time chunk c, neuron slab). Each thread: 4 consecutive
// neurons, float4 stores. Records first spike per batch for the fixup.
__global__ __launch_bounds__(256) void lif_chunks(
    const int* __restrict__ n_steps_p,
    const float* __restrict__ delta_t_p,
    const float* __restrict__ init_v,
    const float* __restrict__ init_Ie,
    const float* __restrict__ init_Ii,
    float* __restrict__ out,
    int* __restrict__ tf,
    int B, int N, int nChunks, int nBlkN)
{
    const int T = n_steps_p[0];
    const float dt = delta_t_p[0] * 0.001f;
    const float aE    = expf(-dt / TAU_SYN_E);
    const float aI    = expf(-dt / TAU_SYN_I);
    const float beta  = expf(-dt / TAU_MEM);
    const float drive = R_CONST * (1.0f - beta);

    int blk = blockIdx.x;
    int bn  = blk % nBlkN;
    int tmp = blk / nBlkN;
    int c   = tmp % nChunks;
    int b   = tmp / nChunks;

    int n = bn * (blockDim.x * 4) + threadIdx.x * 4;
    if (n + 3 >= N + 4) return;           // slab fully out of range
    if (n + 3 >= N) return;               // require full vec4 (N % 4 == 0 assumed)

    const int t0 = c * TCHUNK;
    if (t0 >= T) return;
    const int t1 = (t0 + TCHUNK < T) ? (t0 + TCHUNK) : T;

    size_t base = (size_t)b * N + n;
    float4 v0  = *(const float4*)&init_v [base];
    float4 Ie0 = *(const float4*)&init_Ie[base];
    float4 Ii0 = *(const float4*)&init_Ii[base];

    // closed-form seed at chunk start (entering step t0)
    const float pE = powf(aE,   (float)t0);
    const float pI = powf(aI,   (float)t0);
    const float pB = powf(beta, (float)t0);
    const float gE = drive * (pE - pB) / (aE - beta);
    const float gI = drive * (pI - pB) / (aI - beta);

    float v[4], Ie[4], Ii[4];
    {
        const float* v0p  = (const float*)&v0;
        const float* Iep  = (const float*)&Ie0;
        const float* Iip  = (const float*)&Ii0;
        for (int k = 0; k < 4; ++k) {
            Ie[k] = Iep[k] * pE;
            Ii[k] = Iip[k] * pI;
            v[k]  = U_REST + (v0p[k] - U_REST) * pB + Iep[k] * gE + Iip[k] * gI;
        }
    }

    size_t span = (size_t)B * (size_t)T * (size_t)N;
    float* __restrict__ out_s = out;
    float* __restrict__ out_v = out + span;
    float* __restrict__ out_e = out + 2 * span;
    float* __restrict__ out_i = out + 3 * span;

    bool spiked = false;
    for (int t = t0; t < t1; ++t) {
        float4 sv, vv, ev, iv;
        float* svp = (float*)&sv; float* vvp = (float*)&vv;
        float* evp = (float*)&ev; float* ivp = (float*)&iv;
        for (int k = 0; k < 4; ++k) {
            float Itot = Ie[k] + Ii[k];
            float vn = U_REST + (v[k] - U_REST) * beta + Itot * drive;
            float s = (vn >= THETA) ? 1.0f : 0.0f;
            if (vn >= THETA) {
                vn = U_RESET;
                if (!spiked) { spiked = true; atomicMin(&tf[b], t); }
            }
            v[k] = vn;
            Ie[k] *= aE;
            Ii[k] *= aI;
            svp[k] = s; vvp[k] = vn; evp[k] = Ie[k]; ivp[k] = Ii[k];
        }
        size_t idx = ((size_t)b * T + t) * (size_t)N + n;
        *(float4*)&out_s[idx] = sv;
        *(float4*)&out_v[idx] = vv;
        *(float4*)&out_e[idx] = ev;
        *(float4*)&out_i[idx] = iv;
    }
}

// Correctness fixup: if any spike occurred in batch b, re-simulate the whole
// batch with full recurrent coupling (one block per batch, spike list in LDS)
// and overwrite the outputs. No-op (immediate return) when no spikes.
__global__ __launch_bounds__(1024) void lif_fixup(
    const int* __restrict__ n_steps_p,
    const float* __restrict__ delta_t_p,
    const int* __restrict__ types,
    const float* __restrict__ W,        // raw weights (N x N), row = presynaptic
    const float* __restrict__ Ew_p,
    const float* __restrict__ Iw_p,
    const float* __restrict__ init_v,
    const float* __restrict__ init_Ie,
    const float* __restrict__ init_Ii,
    float* __restrict__ out,
    const int* __restrict__ tf,
    int B, int N)
{
    const int b = blockIdx.x;
    if (tf[b] == NO_SPIKE) return;   // batch never spiked: lif_chunks output exact

    const int T = n_steps_p[0];
    const float dt = delta_t_p[0] * 0.001f;
    const float aE    = expf(-dt / TAU_SYN_E);
    const float aI    = expf(-dt / TAU_SYN_I);
    const float beta  = expf(-dt / TAU_MEM);
    const float drive = R_CONST * (1.0f - beta);
    const float Ew = Ew_p[0];
    const float Iw = Iw_p[0];

    const int NPT = (N + blockDim.x - 1) / blockDim.x;   // 4 for N=4096

    __shared__ int cnt;
    __shared__ int slist[4096];

    float v[8], Ie[8], Ii[8], sc[8];
    int   nn[8];
    for (int k = 0; k < NPT; ++k) {
        int n = threadIdx.x + k * blockDim.x;
        nn[k] = n;
        if (n < N) {
            v[k]  = init_v[(size_t)b * N + n];
            Ie[k] = init_Ie[(size_t)b * N + n];
            Ii[k] = init_Ii[(size_t)b * N + n];
            sc[k] = (types[n] == 1) ? Ew : Iw;   // column (postsynaptic) scale
        }
    }

    size_t span = (size_t)B * (size_t)T * (size_t)N;
    float* __restrict__ out_s = out;
    float* __restrict__ out_v = out + span;
    float* __restrict__ out_e = out + 2 * span;
    float* __restrict__ out_i = out + 3 * span;

    for (int t = 0; t < T; ++t) {
        if (threadIdx.x == 0) cnt = 0;
        __syncthreads();

        for (int k = 0; k < NPT; ++k) {
            if (nn[k] >= N) continue;
            float Itot = Ie[k] + Ii[k];
            float vv = U_REST + (v[k] - U_REST) * beta + Itot * drive;
            float s = (vv >= THETA) ? 1.0f : 0.0f;
            if (vv >= THETA) {
                vv = U_RESET;
                int p = atomicAdd(&cnt, 1);
                slist[p] = nn[k];
            }
            v[k] = vv;
            size_t idx = (size_t)b * (size_t)T * N + (size_t)t * N + nn[k];
            out_s[idx] = s;
            out_v[idx] = vv;
        }
        __syncthreads();

        int c = cnt;
        for (int k = 0; k < NPT; ++k) {
            if (nn[k] >= N) continue;
            float accE = 0.0f, accI = 0.0f;
            for (int q = 0; q < c; ++q) {
                int j = slist[q];
                float w = W[(size_t)j * N + nn[k]];
                if (types[j] == 1) accE += w; else accI += w;
            }
            Ie[k] = Ie[k] * aE + accE * sc[k];
            Ii[k] = Ii[k] * aI + accI * sc[k];
            size_t idx = (size_t)b * (size_t)T * N + (size_t)t * N + nn[k];
            out_e[idx] = Ie[k];
            out_i[idx] = Ii[k];
        }
        __syncthreads();
    }
}

extern "C" void kernel_launch(void* const* d_in, const int* in_sizes, int n_in,
                              void* d_out, int out_size, void* d_ws, size_t ws_size,
                              hipStream_t stream) {
    const int*   n_steps = (const int*)d_in[0];
    const float* delta_t = (const float*)d_in[1];
    const int*   types   = (const int*)d_in[2];
    const float* W       = (const float*)d_in[3];
    const float* Ew      = (const float*)d_in[4];
    const float* Iw      = (const float*)d_in[5];
    const float* init_v  = (const float*)d_in[6];
    const float* init_Ie = (const float*)d_in[7];
    const float* init_Ii = (const float*)d_in[8];
    float* out = (float*)d_out;

    const int N = in_sizes[2];
    const int B = in_sizes[6] / N;
    const int T = out_size / (4 * B * N);   // 4 stacked outputs of B*T*N
    int* tf = (int*)d_ws;

    hipLaunchKernelGGL(lif_init_tfirst, dim3(1), dim3(64), 0, stream, tf, B);

    const int nChunks = (T + TCHUNK - 1) / TCHUNK;
    const int nBlkN   = (N + 1023) / 1024;   // 256 threads * 4 elems
    const int nBlocks = B * nChunks * nBlkN;
    hipLaunchKernelGGL(lif_chunks, dim3(nBlocks), dim3(256), 0, stream,
                       n_steps, delta_t, init_v, init_Ie, init_Ii, out, tf,
                       B, N, nChunks, nBlkN);

    hipLaunchKernelGGL(lif_fixup, dim3(B), dim3(1024), 0, stream,
                       n_steps, delta_t, types, W, Ew, Iw,
                       init_v, init_Ie, init_Ii, out, tf, B, N);
}

// Round 4
// 312.117 us; speedup vs baseline: 1.0167x; 1.0146x over previous
//
#include <hip/hip_runtime.h>
#include <math.h>

// Physiological constants (match reference; E/I membrane constants are equal)
#define TAU_SYN_E 0.005f
#define TAU_SYN_I 0.01f
#define TAU_MEM   0.02f
#define U_REST    (-65.0f)
#define THETA     (-50.0f)
#define U_RESET   (-65.0f)
#define R_CONST   0.1f

#define TCHUNK 10

// native vector type — __builtin_nontemporal_store requires a non-class type
typedef float vfloat4 __attribute__((ext_vector_type(4)));

// Time-parallel independent-neuron simulation. Valid while no spike has
// occurred in the batch (linear dynamics -> closed-form chunk seed). Each
// block: (batch b, time chunk c, neuron slab). Each thread: 4 consecutive
// neurons, nontemporal float4 stores (write-once data, bypass L2).
// tf[b] is pre-set to 0x7F7F7F7F (>=T) by hipMemsetAsync; any spike does
// atomicMin so the fixup kernel can repair that batch.
__global__ __launch_bounds__(256) void lif_chunks(
    const int* __restrict__ n_steps_p,
    const float* __restrict__ delta_t_p,
    const float* __restrict__ init_v,
    const float* __restrict__ init_Ie,
    const float* __restrict__ init_Ii,
    float* __restrict__ out,
    int* __restrict__ tf,
    int B, int N, int nChunks, int nBlkN)
{
    const int T = n_steps_p[0];
    const float dt = delta_t_p[0] * 0.001f;
    const float aE    = expf(-dt / TAU_SYN_E);
    const float aI    = expf(-dt / TAU_SYN_I);
    const float beta  = expf(-dt / TAU_MEM);
    const float drive = R_CONST * (1.0f - beta);

    int blk = blockIdx.x;
    int bn  = blk % nBlkN;
    int tmp = blk / nBlkN;
    int c   = tmp % nChunks;
    int b   = tmp / nChunks;

    int n = bn * (blockDim.x * 4) + threadIdx.x * 4;
    if (n + 3 >= N) return;               // full vec4 only (N % 4 == 0)

    const int t0 = c * TCHUNK;
    if (t0 >= T) return;
    const int t1 = (t0 + TCHUNK < T) ? (t0 + TCHUNK) : T;

    size_t base = (size_t)b * N + n;
    vfloat4 v0  = *(const vfloat4*)&init_v [base];
    vfloat4 Ie0 = *(const vfloat4*)&init_Ie[base];
    vfloat4 Ii0 = *(const vfloat4*)&init_Ii[base];

    // closed-form seed at chunk start (state entering step t0)
    const float pE = powf(aE,   (float)t0);
    const float pI = powf(aI,   (float)t0);
    const float pB = powf(beta, (float)t0);
    const float gE = drive * (pE - pB) / (aE - beta);
    const float gI = drive * (pI - pB) / (aI - beta);

    float v[4], Ie[4], Ii[4];
    for (int k = 0; k < 4; ++k) {
        Ie[k] = Ie0[k] * pE;
        Ii[k] = Ii0[k] * pI;
        v[k]  = U_REST + (v0[k] - U_REST) * pB + Ie0[k] * gE + Ii0[k] * gI;
    }

    size_t span = (size_t)B * (size_t)T * (size_t)N;
    float* __restrict__ out_s = out;
    float* __restrict__ out_v = out + span;
    float* __restrict__ out_e = out + 2 * span;
    float* __restrict__ out_i = out + 3 * span;

    bool spiked = false;
    for (int t = t0; t < t1; ++t) {
        vfloat4 sv, vv, ev, iv;
        for (int k = 0; k < 4; ++k) {
            float Itot = Ie[k] + Ii[k];
            float vn = U_REST + (v[k] - U_REST) * beta + Itot * drive;
            float s = (vn >= THETA) ? 1.0f : 0.0f;
            if (vn >= THETA) {
                vn = U_RESET;
                if (!spiked) { spiked = true; atomicMin(&tf[b], t); }
            }
            v[k] = vn;
            Ie[k] *= aE;
            Ii[k] *= aI;
            sv[k] = s; vv[k] = vn; ev[k] = Ie[k]; iv[k] = Ii[k];
        }
        size_t idx = ((size_t)b * T + t) * (size_t)N + n;
        __builtin_nontemporal_store(sv, (vfloat4*)&out_s[idx]);
        __builtin_nontemporal_store(vv, (vfloat4*)&out_v[idx]);
        __builtin_nontemporal_store(ev, (vfloat4*)&out_e[idx]);
        __builtin_nontemporal_store(iv, (vfloat4*)&out_i[idx]);
    }
}

// Correctness fixup: if any spike occurred in batch b, re-simulate the whole
// batch with full recurrent coupling (one block per batch, spike list in LDS)
// and overwrite the outputs. No-op (immediate return) when no spikes.
__global__ __launch_bounds__(1024) void lif_fixup(
    const int* __restrict__ n_steps_p,
    const float* __restrict__ delta_t_p,
    const int* __restrict__ types,
    const float* __restrict__ W,        // raw weights (N x N), row = presynaptic
    const float* __restrict__ Ew_p,
    const float* __restrict__ Iw_p,
    const float* __restrict__ init_v,
    const float* __restrict__ init_Ie,
    const float* __restrict__ init_Ii,
    float* __restrict__ out,
    const int* __restrict__ tf,
    int B, int N)
{
    const int b = blockIdx.x;
    const int T = n_steps_p[0];
    if (tf[b] >= T) return;   // batch never spiked: lif_chunks output exact

    const float dt = delta_t_p[0] * 0.001f;
    const float aE    = expf(-dt / TAU_SYN_E);
    const float aI    = expf(-dt / TAU_SYN_I);
    const float beta  = expf(-dt / TAU_MEM);
    const float drive = R_CONST * (1.0f - beta);
    const float Ew = Ew_p[0];
    const float Iw = Iw_p[0];

    const int NPT = (N + blockDim.x - 1) / blockDim.x;   // 4 for N=4096

    __shared__ int cnt;
    __shared__ int slist[4096];

    float v[8], Ie[8], Ii[8], sc[8];
    int   nn[8];
    for (int k = 0; k < NPT; ++k) {
        int n = threadIdx.x + k * blockDim.x;
        nn[k] = n;
        if (n < N) {
            v[k]  = init_v[(size_t)b * N + n];
            Ie[k] = init_Ie[(size_t)b * N + n];
            Ii[k] = init_Ii[(size_t)b * N + n];
            sc[k] = (types[n] == 1) ? Ew : Iw;   // column (postsynaptic) scale
        }
    }

    size_t span = (size_t)B * (size_t)T * (size_t)N;
    float* __restrict__ out_s = out;
    float* __restrict__ out_v = out + span;
    float* __restrict__ out_e = out + 2 * span;
    float* __restrict__ out_i = out + 3 * span;

    for (int t = 0; t < T; ++t) {
        if (threadIdx.x == 0) cnt = 0;
        __syncthreads();

        for (int k = 0; k < NPT; ++k) {
            if (nn[k] >= N) continue;
            float Itot = Ie[k] + Ii[k];
            float vv = U_REST + (v[k] - U_REST) * beta + Itot * drive;
            float s = (vv >= THETA) ? 1.0f : 0.0f;
            if (vv >= THETA) {
                vv = U_RESET;
                int p = atomicAdd(&cnt, 1);
                slist[p] = nn[k];
            }
            v[k] = vv;
            size_t idx = (size_t)b * (size_t)T * N + (size_t)t * N + nn[k];
            out_s[idx] = s;
            out_v[idx] = vv;
        }
        __syncthreads();

        int c = cnt;
        for (int k = 0; k < NPT; ++k) {
            if (nn[k] >= N) continue;
            float accE = 0.0f, accI = 0.0f;
            for (int q = 0; q < c; ++q) {
                int j = slist[q];
                float w = W[(size_t)j * N + nn[k]];
                if (types[j] == 1) accE += w; else accI += w;
            }
            Ie[k] = Ie[k] * aE + accE * sc[k];
            Ii[k] = Ii[k] * aI + accI * sc[k];
            size_t idx = (size_t)b * (size_t)T * N + (size_t)t * N + nn[k];
            out_e[idx] = Ie[k];
            out_i[idx] = Ii[k];
        }
        __syncthreads();
    }
}

extern "C" void kernel_launch(void* const* d_in, const int* in_sizes, int n_in,
                              void* d_out, int out_size, void* d_ws, size_t ws_size,
                              hipStream_t stream) {
    const int*   n_steps = (const int*)d_in[0];
    const float* delta_t = (const float*)d_in[1];
    const int*   types   = (const int*)d_in[2];
    const float* W       = (const float*)d_in[3];
    const float* Ew      = (const float*)d_in[4];
    const float* Iw      = (const float*)d_in[5];
    const float* init_v  = (const float*)d_in[6];
    const float* init_Ie = (const float*)d_in[7];
    const float* init_Ii = (const float*)d_in[8];
    float* out = (float*)d_out;

    const int N = in_sizes[2];
    const int B = in_sizes[6] / N;
    const int T = out_size / (4 * B * N);   // 4 stacked outputs of B*T*N
    int* tf = (int*)d_ws;

    // tf[b] = 0x7F7F7F7F (>= T) : "no spike yet". Capture-safe async memset.
    (void)hipMemsetAsync(tf, 0x7F, (size_t)B * sizeof(int), stream);

    const int nChunks = (T + TCHUNK - 1) / TCHUNK;
    const int nBlkN   = (N + 1023) / 1024;   // 256 threads * 4 elems
    const int nBlocks = B * nChunks * nBlkN;
    hipLaunchKernelGGL(lif_chunks, dim3(nBlocks), dim3(256), 0, stream,
                       n_steps, delta_t, init_v, init_Ie, init_Ii, out, tf,
                       B, N, nChunks, nBlkN);

    hipLaunchKernelGGL(lif_fixup, dim3(B), dim3(1024), 0, stream,
                       n_steps, delta_t, types, W, Ew, Iw,
                       init_v, init_Ie, init_Ii, out, tf, B, N);
}